// Round 5
// baseline (32354.141 us; speedup 1.0000x reference)
//
#include <hip/hip_runtime.h>
#include <math.h>

#define NN 32
#define PADL 36   // L buffer column stride (f32): float4-aligned chunks, +32 slot holds 1/diag
#define PADT 34   // transpose-style stride: even (float2-aligned), <=2-way conflicts (free)
#define NSWEEP 6

__device__ __forceinline__ float bperm(int addr, float x) {
  return __int_as_float(__builtin_amdgcn_ds_bpermute(addr, __float_as_int(x)));
}

// ---------------- one-sided Jacobi (XOR cyclic ordering, EXACT rotation updates) --------
// g[]: this lane's column of a 32x32 matrix G (lane l5 of each 32-half owns col l5).
// Orthogonalizes columns (right rotations): on exit g = U*sigma, nrm = sigma^2 (exact).
// For symmetric input C: sigma = eigenvalue; for general G: sigma^2 = eig of G G^T.
__device__ __forceinline__ void jacobi_sweeps(float g[NN], float &nrm) {
  const int lane = threadIdx.x & 63;
  {
    float a0=0.f,a1=0.f,a2=0.f,a3=0.f;
    #pragma unroll
    for (int i = 0; i < NN; i += 4) {
      a0 = fmaf(g[i+0],g[i+0],a0); a1 = fmaf(g[i+1],g[i+1],a1);
      a2 = fmaf(g[i+2],g[i+2],a2); a3 = fmaf(g[i+3],g[i+3],a3);
    }
    nrm = (a0+a1)+(a2+a3);
  }
  #pragma unroll 1
  for (int sw = 0; sw < NSWEEP; ++sw) {
    bool act = false;
    #pragma unroll 1
    for (int m = 1; m < NN; ++m) {
      const int addr = ((lane ^ m) << 2);
      float p[NN];
      #pragma unroll
      for (int i = 0; i < NN; ++i) p[i] = bperm(addr, g[i]);
      float d0=0.f,d1=0.f,d2=0.f,d3=0.f;
      #pragma unroll
      for (int i = 0; i < NN; i += 4) {
        d0 = fmaf(g[i+0], p[i+0], d0); d1 = fmaf(g[i+1], p[i+1], d1);
        d2 = fmaf(g[i+2], p[i+2], d2); d3 = fmaf(g[i+3], p[i+3], d3);
      }
      float d = (d0+d1)+(d2+d3);
      float other = bperm(addr, nrm);
      const bool isP = (((lane ^ m) & 31) > (lane & 31));
      float pn = isP ? nrm : other;       // shared p-perspective (identical on the pair)
      float qn = isP ? other : nrm;
      float delta = pn - qn;
      float dd = d * d;
      act = act || (dd > 1e-10f * (pn * qn));   // |cos theta| > 1e-5: not converged
      float r2 = fmaf(delta, delta, 4.f * dd);
      float R  = r2 * rsqrtf(fmaxf(r2, 1e-37f));   // sqrt(r2), 0-safe
      float den = delta + copysignf(R + 1e-30f, delta);
      float t = (-2.f * d) * __builtin_amdgcn_rcpf(den);  // small-|t| root of d t^2 - delta t - d = 0
      float c = rsqrtf(fmaf(t, t, 1.f));
      float s = t * c;
      float sg = isP ? -s : s;            // p: c*gp - s*gq ; q: c*gq + s*gp
      #pragma unroll
      for (int i = 0; i < NN; ++i) g[i] = fmaf(sg, p[i], c*g[i]);
      float csd2 = 2.f*c*s*d;
      nrm = c*c*nrm + s*s*other + (isP ? -csd2 : csd2);
    }
    if (!__any(act)) break;               // wave-wide convergence (both halves)
  }
  // exact norm recompute (analytic updates drift slightly)
  float a0=0.f,a1=0.f,a2=0.f,a3=0.f;
  #pragma unroll
  for (int i = 0; i < NN; i += 4) {
    a0 = fmaf(g[i+0],g[i+0],a0); a1 = fmaf(g[i+1],g[i+1],a1);
    a2 = fmaf(g[i+2],g[i+2],a2); a3 = fmaf(g[i+3],g[i+3],a3);
  }
  nrm = (a0+a1)+(a2+a3);
}

// ---------------- Cholesky: m[] (col of SPD M, in place -> col of L) ----------------
// EXACT round-2 form: gt guard keeps finalized columns intact (round-3 dropped it => bug).
// Lbuf[c*PADL + r] = L[r][c]; 1/L[j][j] at Lbuf[j*PADL+32].
__device__ __forceinline__ void cholesky32(float m[NN], float *Lbuf, int l5) {
  float myinvd = 0.f;
  #pragma unroll
  for (int j = 0; j < NN; ++j) {
    float bj   = __shfl(m[j], j, 32);      // current Schur diagonal
    float invd = rsqrtf(bj);               // 1/L[j][j]
    float lkj  = m[j] * invd;              // own L[lane][j] (valid lanes >= j by symmetry)
    bool isj = (l5 == j), gt = (l5 > j);
    myinvd = isj ? invd : myinvd;
    #pragma unroll
    for (int i = j; i < NN; ++i) {
      float bi  = __shfl(m[i], j, 32);
      float lij = bi * invd;
      float upd = fmaf(-lij, lkj, m[i]);
      m[i] = isj ? lij : (gt ? upd : m[i]);  // lanes < j: column final, DO NOT touch
    }
  }
  #pragma unroll
  for (int i = 0; i < NN; i += 4)
    *(float4*)&Lbuf[l5*PADL + i] = make_float4(m[i], m[i+1], m[i+2], m[i+3]);
  Lbuf[l5*PADL + 32] = myinvd;
}

// ---------------- forward triangular solve: x := L^-1 x (x = lane-owned RHS column) ----
__device__ __forceinline__ void trsv32(float x[NN], const float *Lbuf) {
  #pragma unroll
  for (int j = 0; j < NN; ++j) {
    float yj = x[j] * Lbuf[j*PADL + 32];
    x[j] = yj;
    #pragma unroll
    for (int i0 = ((j+1) & ~3); i0 < NN; i0 += 4) {
      float4 Lc = *(const float4*)&Lbuf[j*PADL + i0];
      if (i0+0 > j) x[i0+0] = fmaf(-Lc.x, yj, x[i0+0]);
      if (i0+1 > j) x[i0+1] = fmaf(-Lc.y, yj, x[i0+1]);
      if (i0+2 > j) x[i0+2] = fmaf(-Lc.z, yj, x[i0+2]);
      if (i0+3 > j) x[i0+3] = fmaf(-Lc.w, yj, x[i0+3]);
    }
  }
}

// ---------------- 32x32 transpose of lane-owned columns via LDS (fallback path) --------
__device__ __forceinline__ void transpose32(float x[NN], float *Tbuf, int l5) {
  __syncthreads();
  #pragma unroll
  for (int i = 0; i < NN; i += 2)
    *(float2*)&Tbuf[l5*PADT + i] = make_float2(x[i], x[i+1]);
  __syncthreads();
  #pragma unroll
  for (int i = 0; i < NN; ++i) x[i] = Tbuf[i*PADT + l5];
}

// ---------------- z = L * us (L lower-tri from Lbuf, us lane-owned column) ----------
__device__ __forceinline__ void trmul_L(const float us[NN], float z[NN], const float *Lbuf) {
  #pragma unroll
  for (int i = 0; i < NN; ++i) z[i] = 0.f;
  #pragma unroll
  for (int k = 0; k < NN; ++k) {
    float uk = us[k];
    #pragma unroll
    for (int i0 = (k & ~3); i0 < NN; i0 += 4) {
      float4 Lc = *(const float4*)&Lbuf[k*PADL + i0];
      if (i0+0 >= k) z[i0+0] = fmaf(Lc.x, uk, z[i0+0]);
      if (i0+1 >= k) z[i0+1] = fmaf(Lc.y, uk, z[i0+1]);
      if (i0+2 >= k) z[i0+2] = fmaf(Lc.z, uk, z[i0+2]);
      if (i0+3 >= k) z[i0+3] = fmaf(Lc.w, uk, z[i0+3]);
    }
  }
}

// ---------------- out := Z * Z^T (Z = lane-owned columns), via LDS (PADT stride) -------
__device__ __forceinline__ void zzT(const float z[NN], float out[NN], float *Tbuf, int l5) {
  __syncthreads();
  #pragma unroll
  for (int i = 0; i < NN; i += 2)
    *(float2*)&Tbuf[l5*PADT + i] = make_float2(z[i], z[i+1]);
  __syncthreads();
  #pragma unroll
  for (int i = 0; i < NN; ++i) out[i] = 0.f;
  #pragma unroll 1
  for (int k = 0; k < NN; ++k) {
    float zjk = Tbuf[k*PADT + l5];           // Z[l5][k] (vector read, conflict-free)
    #pragma unroll
    for (int i = 0; i < NN; i += 2) {
      float2 c2 = *(const float2*)&Tbuf[k*PADT + i];   // broadcast b64 reads
      out[i+0] = fmaf(c2.x, zjk, out[i+0]);
      out[i+1] = fmaf(c2.y, zjk, out[i+1]);
    }
  }
}

// ================= K0: weight tables =================
__global__ void k_tables(const float* __restrict__ W, float* __restrict__ tfwd,
                         float* __restrict__ trev, float* __restrict__ wnn) {
  int o = threadIdx.x;
  if (o >= NN) return;
  float w[NN];
  #pragma unroll 1
  for (int i = 0; i < NN; ++i) w[i] = fminf(fmaxf(W[o*NN+i], 0.001f), 0.999f);
  float cs = 0.f;
  #pragma unroll 1
  for (int i = 0; i < NN; ++i) { cs += w[i]; tfwd[o*NN+i] = w[i]/cs; }
  float tot = cs;
  #pragma unroll 1
  for (int i = 0; i < NN; ++i) wnn[o*NN+i] = w[i]/tot;
  cs = 0.f;
  #pragma unroll 1
  for (int i = 0; i < NN; ++i) { cs += w[NN-1-i]; trev[o*NN+i] = w[NN-1-i]/cs; }
}

// ================= K1: Llog[b,i] = logm(X[b,i]) =================
__global__ __launch_bounds__(64) void k_logm(const float* __restrict__ x,
                                             float* __restrict__ llog) {
  __shared__ float Tbuf[2][NN*PADT];
  int lane = threadIdx.x, half = lane >> 5, l5 = lane & 31;
  int P = blockIdx.x*2 + half;                  // b*I + i
  const float* xp = x + (size_t)P*1024 + l5;
  float g[NN];
  #pragma unroll
  for (int i = 0; i < NN; ++i) g[i] = xp[i*NN];
  float nrm;
  jacobi_sweeps(g, nrm);                        // X SPD: columns = U*lam, nrm = lam^2
  float lg   = 0.5f * log2f(fmaxf(nrm, 1e-12f)); // log2(lambda)
  float lnl  = lg * 0.69314718056f;              // ln(lambda)
  float invl = exp2f(-lg);                       // 1/lambda
  float *Tb = Tbuf[half];
  __syncthreads();
  #pragma unroll
  for (int i = 0; i < NN; i += 2)
    *(float2*)&Tb[l5*PADT + i] = make_float2(g[i]*invl, g[i+1]*invl);  // U columns
  Tb[l5*PADT + 32] = lnl;
  __syncthreads();
  float m[NN];
  #pragma unroll
  for (int i = 0; i < NN; ++i) m[i] = 0.f;
  #pragma unroll 1
  for (int k = 0; k < NN; ++k) {
    float coef = Tb[k*PADT + 32] * Tb[k*PADT + l5];  // ln(lam_k) * U[l5][k]
    #pragma unroll
    for (int i = 0; i < NN; i += 2) {
      float2 c2 = *(const float2*)&Tb[k*PADT + i];
      m[i+0] = fmaf(c2.x, coef, m[i+0]);
      m[i+1] = fmaf(c2.y, coef, m[i+1]);
    }
  }
  float* op = llog + (size_t)P*1024 + l5;
  #pragma unroll
  for (int i = 0; i < NN; ++i) op[i*NN] = m[i];
}

// ================= K2: out3 = expm( sum_i wnn[o,i] * Llog[b,i] ) =================
__global__ __launch_bounds__(64) void k_fastfm(const float* __restrict__ llog,
                                               const float* __restrict__ wnn,
                                               float* __restrict__ out3) {
  __shared__ float Tbuf[2][NN*PADT];
  int lane = threadIdx.x, half = lane >> 5, l5 = lane & 31;
  int P = blockIdx.x*2 + half;                  // b*O + o
  int b = P >> 5, o = P & 31;
  float acc[NN];
  #pragma unroll
  for (int i = 0; i < NN; ++i) acc[i] = 0.f;
  const float* lp = llog + (size_t)b*NN*1024 + l5;
  #pragma unroll 1
  for (int i2 = 0; i2 < NN; ++i2) {
    float w = wnn[o*NN + i2];
    const float* q = lp + (size_t)i2*1024;
    #pragma unroll
    for (int i = 0; i < NN; ++i) acc[i] = fmaf(q[i*NN], w, acc[i]);
  }
  // shift by +4I so the matrix is SPD; expm(M) = e^-4 expm(M+4I)
  #pragma unroll
  for (int i = 0; i < NN; ++i) acc[i] += (i == l5) ? 4.0f : 0.0f;
  float nrm;
  jacobi_sweeps(acc, nrm);
  float lg  = 0.5f * log2f(fmaxf(nrm, 1e-12f));
  float lam = exp2f(lg);                        // shifted eigenvalue (lam_true + 4)
  float sc  = expf(0.5f*(lam - 4.0f)) * exp2f(-lg);  // exp(lam_true/2)/lam
  #pragma unroll
  for (int i = 0; i < NN; ++i) acc[i] *= sc;    // Us columns
  float m3[NN];
  zzT(acc, m3, Tbuf[half], l5);                 // Us Us^T
  float* op = out3 + (size_t)P*1024 + l5;
  #pragma unroll
  for (int i = 0; i < NN; ++i) op[i*NN] = m3[i];
}

// ================= K2.5: R[b,i] = chol(X[b,i]), zero-filled upper =================
__global__ __launch_bounds__(64) void k_cholx(const float* __restrict__ x,
                                              float* __restrict__ Rg) {
  int lane = threadIdx.x, half = lane >> 5, l5 = lane & 31;
  int P = blockIdx.x*2 + half;                  // b*I + i
  const float* xp = x + (size_t)P*1024 + l5;
  float m[NN];
  #pragma unroll
  for (int i = 0; i < NN; ++i) m[i] = xp[i*NN];
  #pragma unroll
  for (int j = 0; j < NN; ++j) {
    float bj   = __shfl(m[j], j, 32);
    float invd = rsqrtf(bj);
    float lkj  = m[j] * invd;
    bool isj = (l5 == j), gt = (l5 > j);
    #pragma unroll
    for (int i = j; i < NN; ++i) {
      float bi  = __shfl(m[i], j, 32);
      float lij = bi * invd;
      float upd = fmaf(-lij, lkj, m[i]);
      m[i] = isj ? lij : (gt ? upd : m[i]);
    }
  }
  float* op = Rg + (size_t)P*1024 + l5;
  #pragma unroll
  for (int i = 0; i < NN; ++i) op[i*NN] = (i >= l5) ? m[i] : 0.f;  // lower-tri column
}

// ================= K3a: recursive scan, precomputed-R path =================
// Per step: M = L L^T (chol); G = L^-1 R_k (ONE trsv, no transpose — G's Jacobi is
// the SVD: G = U*sig, sig^2 = eig(C), C = G G^T = L^-1 X_k L^-T); Z = L*U*sig^t;
// M' = Z Z^T. Union LDS buffer (L and transpose staging never live simultaneously).
__global__ __launch_bounds__(64) void k_rec_pre(const float* __restrict__ Rg,
    const float* __restrict__ tfwd, const float* __restrict__ trev,
    float* __restrict__ out1, float* __restrict__ out2) {
  __shared__ __align__(16) float Ub[2][NN*PADL];   // union: Lbuf / zzT staging
  int lane = threadIdx.x, half = lane >> 5, l5 = lane & 31;
  int P = blockIdx.x*2 + half;                  // 0..16383
  int dir = P >> 13;                            // B*O = 8192 per direction
  int rem = P & 8191;
  int b = rem >> 5, o = rem & 31;
  const float* tt = dir ? trev : tfwd;
  float* outp = (dir ? out2 : out1) + (size_t)(b*NN + o)*1024;
  const float* Rb = Rg + (size_t)b*NN*1024;
  float *Uh = Ub[half];

  float m[NN], rk[NN];
  {
    const float* rp = Rb + (size_t)(dir ? (NN-1) : 0)*1024 + l5;
    #pragma unroll
    for (int i = 0; i < NN; ++i) rk[i] = rp[i*NN];
    zzT(rk, m, Uh, l5);                           // M0 = R0 R0^T = X0
  }
  #pragma unroll 1
  for (int j = 1; j < NN; ++j) {
    int k = dir ? (NN-1-j) : j;
    const float* rp = Rb + (size_t)k*1024 + l5;   // issue loads early; used after chol
    #pragma unroll
    for (int i = 0; i < NN; ++i) rk[i] = rp[i*NN];
    float tv = tt[o*NN + j];

    cholesky32(m, Uh, l5);                        // M = L L^T (writes Uh)
    trsv32(rk, Uh);                               // G = L^-1 R_k
    float nrm;
    jacobi_sweeps(rk, nrm);                       // G = U*sig, nrm = sig^2 = eig(C)
    // Us = U * lam^{t/2} = g * lam^{(t-1)/2},  lam = nrm
    float lg = log2f(fmaxf(nrm, 1e-12f));
    float sc = exp2f(lg * 0.5f * (tv - 1.0f));
    #pragma unroll
    for (int i = 0; i < NN; ++i) rk[i] *= sc;
    float z[NN];
    trmul_L(rk, z, Uh);                           // Z = L * Us
    zzT(z, m, Uh, l5);                            // M' = Z Z^T (L dead by now; union safe)
  }
  #pragma unroll
  for (int i = 0; i < NN; ++i) outp[i*NN + l5] = m[i];
}

// ================= K3b: fallback (ws too small): round-2 structure =================
__global__ __launch_bounds__(64) void k_rec_fb(const float* __restrict__ x,
    const float* __restrict__ tfwd, const float* __restrict__ trev,
    float* __restrict__ out1, float* __restrict__ out2) {
  __shared__ __align__(16) float Lbuf[2][NN*PADL];
  __shared__ float Tbuf[2][NN*PADT];
  int lane = threadIdx.x, half = lane >> 5, l5 = lane & 31;
  int P = blockIdx.x*2 + half;
  int dir = P >> 13;
  int rem = P & 8191;
  int b = rem >> 5, o = rem & 31;
  const float* tt = dir ? trev : tfwd;
  float* outp = (dir ? out2 : out1) + (size_t)(b*NN + o)*1024;
  const float* xb = x + (size_t)b*NN*1024;
  float *Lb = Lbuf[half], *Tb = Tbuf[half];

  float m[NN];
  {
    const float* xp = xb + (size_t)(dir ? (NN-1) : 0)*1024 + l5;
    #pragma unroll
    for (int i = 0; i < NN; ++i) m[i] = xp[i*NN];
  }
  #pragma unroll 1
  for (int j = 1; j < NN; ++j) {
    int k = dir ? (NN-1-j) : j;
    float xk[NN];
    const float* xp = xb + (size_t)k*1024 + l5;
    #pragma unroll
    for (int i = 0; i < NN; ++i) xk[i] = xp[i*NN];
    float tv = tt[o*NN + j];

    cholesky32(m, Lb, l5);
    trsv32(xk, Lb);
    transpose32(xk, Tb, l5);
    trsv32(xk, Lb);                               // C = L^-1 X L^-T
    float nrm;
    jacobi_sweeps(xk, nrm);                       // C = U*lam, nrm = lam^2
    float lg = 0.5f * log2f(fmaxf(nrm, 1e-12f));
    float sc = exp2f(lg * (0.5f*tv - 1.0f));
    #pragma unroll
    for (int i = 0; i < NN; ++i) xk[i] *= sc;
    float z[NN];
    trmul_L(xk, z, Lb);
    zzT(z, m, Tb, l5);
  }
  #pragma unroll
  for (int i = 0; i < NN; ++i) outp[i*NN + l5] = m[i];
}

extern "C" void kernel_launch(void* const* d_in, const int* in_sizes, int n_in,
                              void* d_out, int out_size, void* d_ws, size_t ws_size,
                              hipStream_t stream) {
  (void)in_sizes; (void)n_in; (void)out_size;
  const float* x = (const float*)d_in[0];
  const float* W = (const float*)d_in[1];
  float* out  = (float*)d_out;
  float* ws   = (float*)d_ws;
  float* tfwd = ws;
  float* trev = ws + 1024;
  float* wnn  = ws + 2048;
  float* Rg   = ws + 3072;                       // 32 MiB if available
  float* out1 = out;
  float* out2 = out + 8388608;
  float* out3 = out + 16777216;
  float* llog = out1;                            // consumed by k_fastfm before k_rec_*

  const size_t need = (size_t)(3072 + 8388608) * sizeof(float);
  const bool pre = (ws_size >= need);

  hipLaunchKernelGGL(k_tables,    dim3(1),    dim3(64), 0, stream, W, tfwd, trev, wnn);
  hipLaunchKernelGGL(k_logm,      dim3(4096), dim3(64), 0, stream, x, llog);
  hipLaunchKernelGGL(k_fastfm,    dim3(4096), dim3(64), 0, stream, llog, wnn, out3);
  if (pre) {
    hipLaunchKernelGGL(k_cholx,   dim3(4096), dim3(64), 0, stream, x, Rg);
    hipLaunchKernelGGL(k_rec_pre, dim3(8192), dim3(64), 0, stream, Rg, tfwd, trev, out1, out2);
  } else {
    hipLaunchKernelGGL(k_rec_fb,  dim3(8192), dim3(64), 0, stream, x, tfwd, trev, out1, out2);
  }
}

// Round 7
// 26862.360 us; speedup vs baseline: 1.2044x; 1.2044x over previous
//
#include <hip/hip_runtime.h>
#include <math.h>

#define NN 32
#define PADL 36   // L buffer column stride (f32): float4-aligned chunks, +32 slot holds 1/diag
#define PADT 34   // transpose-style stride: even (float2-aligned), <=2-way conflicts (free)
#define NSWEEP 6

// ---------------- one-sided Jacobi (XOR cyclic ordering, EXACT rotation updates) --------
// g[]: this lane's column of a 32x32 matrix G (lane l5 of each 32-half owns col l5).
// Orthogonalizes columns (right rotations): on exit g = U*sigma, nrm = sigma^2 (exact).
// For symmetric input C: sigma = eigenvalue; for general G: sigma^2 = eig of G G^T.
__device__ __forceinline__ void jacobi_sweeps(float g[NN], float &nrm) {
  {
    float a0=0.f,a1=0.f,a2=0.f,a3=0.f;
    #pragma unroll
    for (int i = 0; i < NN; i += 4) {
      a0 = fmaf(g[i+0],g[i+0],a0); a1 = fmaf(g[i+1],g[i+1],a1);
      a2 = fmaf(g[i+2],g[i+2],a2); a3 = fmaf(g[i+3],g[i+3],a3);
    }
    nrm = (a0+a1)+(a2+a3);
  }
  const int l5 = threadIdx.x & 31;
  #pragma unroll 1
  for (int sw = 0; sw < NSWEEP; ++sw) {
    bool act = false;
    #pragma unroll 1
    for (int m = 1; m < NN; ++m) {
      float p[NN];
      #pragma unroll
      for (int i = 0; i < NN; ++i) p[i] = __shfl_xor(g[i], m);
      float d0=0.f,d1=0.f,d2=0.f,d3=0.f;
      #pragma unroll
      for (int i = 0; i < NN; i += 4) {
        d0 = fmaf(g[i+0], p[i+0], d0); d1 = fmaf(g[i+1], p[i+1], d1);
        d2 = fmaf(g[i+2], p[i+2], d2); d3 = fmaf(g[i+3], p[i+3], d3);
      }
      float d = (d0+d1)+(d2+d3);
      float other = __shfl_xor(nrm, m);
      const bool isP = (((l5 ^ m) & 31) > l5);   // partner higher index -> we play "p"
      float pn = isP ? nrm : other;       // shared p-perspective (identical on the pair)
      float qn = isP ? other : nrm;
      float delta = pn - qn;
      float dd = d * d;
      act = act || (dd > 1e-10f * (pn * qn));   // |cos theta| > 1e-5: not converged
      float r2 = fmaf(delta, delta, 4.f * dd);
      float R  = r2 * rsqrtf(fmaxf(r2, 1e-37f));   // sqrt(r2), 0-safe
      float den = delta + copysignf(R + 1e-30f, delta);
      float t = (-2.f * d) * __builtin_amdgcn_rcpf(den);  // small-|t| root of d t^2 - delta t - d = 0
      float c = rsqrtf(fmaf(t, t, 1.f));
      float s = t * c;
      float sg = isP ? -s : s;            // p: c*gp - s*gq ; q: c*gq + s*gp
      #pragma unroll
      for (int i = 0; i < NN; ++i) g[i] = fmaf(sg, p[i], c*g[i]);
      float csd2 = 2.f*c*s*d;
      nrm = c*c*nrm + s*s*other + (isP ? -csd2 : csd2);
    }
    if (!__any(act)) break;               // wave-wide convergence (both halves)
  }
  // exact norm recompute (analytic updates drift slightly)
  float a0=0.f,a1=0.f,a2=0.f,a3=0.f;
  #pragma unroll
  for (int i = 0; i < NN; i += 4) {
    a0 = fmaf(g[i+0],g[i+0],a0); a1 = fmaf(g[i+1],g[i+1],a1);
    a2 = fmaf(g[i+2],g[i+2],a2); a3 = fmaf(g[i+3],g[i+3],a3);
  }
  nrm = (a0+a1)+(a2+a3);
}

// ---------------- Cholesky: m[] (col of SPD M, in place -> col of L) ----------------
// gt guard is REQUIRED (finalized columns must not take Schur updates).
// Lbuf[c*PADL + r] = L[r][c]; 1/L[j][j] at Lbuf[j*PADL+32].
__device__ __forceinline__ void cholesky32(float m[NN], float *Lbuf, int l5) {
  float myinvd = 0.f;
  #pragma unroll
  for (int j = 0; j < NN; ++j) {
    float bj   = __shfl(m[j], j, 32);      // current Schur diagonal
    float invd = rsqrtf(bj);               // 1/L[j][j]
    float lkj  = m[j] * invd;              // own L[lane][j] (valid lanes >= j by symmetry)
    bool isj = (l5 == j), gt = (l5 > j);
    myinvd = isj ? invd : myinvd;
    #pragma unroll
    for (int i = j; i < NN; ++i) {
      float bi  = __shfl(m[i], j, 32);
      float lij = bi * invd;
      float upd = fmaf(-lij, lkj, m[i]);
      m[i] = isj ? lij : (gt ? upd : m[i]);  // lanes < j: column final, DO NOT touch
    }
  }
  #pragma unroll
  for (int i = 0; i < NN; i += 4)
    *(float4*)&Lbuf[l5*PADL + i] = make_float4(m[i], m[i+1], m[i+2], m[i+3]);
  Lbuf[l5*PADL + 32] = myinvd;
}

// ---------------- forward triangular solve: x := L^-1 x (x = lane-owned RHS column) ----
__device__ __forceinline__ void trsv32(float x[NN], const float *Lbuf) {
  #pragma unroll
  for (int j = 0; j < NN; ++j) {
    float yj = x[j] * Lbuf[j*PADL + 32];
    x[j] = yj;
    #pragma unroll
    for (int i0 = ((j+1) & ~3); i0 < NN; i0 += 4) {
      float4 Lc = *(const float4*)&Lbuf[j*PADL + i0];
      if (i0+0 > j) x[i0+0] = fmaf(-Lc.x, yj, x[i0+0]);
      if (i0+1 > j) x[i0+1] = fmaf(-Lc.y, yj, x[i0+1]);
      if (i0+2 > j) x[i0+2] = fmaf(-Lc.z, yj, x[i0+2]);
      if (i0+3 > j) x[i0+3] = fmaf(-Lc.w, yj, x[i0+3]);
    }
  }
}

// ---------------- 32x32 transpose of lane-owned columns via LDS (fallback path) --------
__device__ __forceinline__ void transpose32(float x[NN], float *Tbuf, int l5) {
  __syncthreads();
  #pragma unroll
  for (int i = 0; i < NN; i += 2)
    *(float2*)&Tbuf[l5*PADT + i] = make_float2(x[i], x[i+1]);
  __syncthreads();
  #pragma unroll
  for (int i = 0; i < NN; ++i) x[i] = Tbuf[i*PADT + l5];
}

// ---------------- z = L * us (L lower-tri from Lbuf, us lane-owned column) ----------
// k-outer: us[k] dies as z fills -> combined liveness stays ~32-64, not 64 flat.
__device__ __forceinline__ void trmul_L(const float us[NN], float z[NN], const float *Lbuf) {
  #pragma unroll
  for (int i = 0; i < NN; ++i) z[i] = 0.f;
  #pragma unroll
  for (int k = 0; k < NN; ++k) {
    float uk = us[k];
    #pragma unroll
    for (int i0 = (k & ~3); i0 < NN; i0 += 4) {
      float4 Lc = *(const float4*)&Lbuf[k*PADL + i0];
      if (i0+0 >= k) z[i0+0] = fmaf(Lc.x, uk, z[i0+0]);
      if (i0+1 >= k) z[i0+1] = fmaf(Lc.y, uk, z[i0+1]);
      if (i0+2 >= k) z[i0+2] = fmaf(Lc.z, uk, z[i0+2]);
      if (i0+3 >= k) z[i0+3] = fmaf(Lc.w, uk, z[i0+3]);
    }
  }
}

// ---------------- out := Z * Z^T (Z = lane-owned columns), via LDS (PADT stride) -------
__device__ __forceinline__ void zzT(const float z[NN], float out[NN], float *Tbuf, int l5) {
  __syncthreads();
  #pragma unroll
  for (int i = 0; i < NN; i += 2)
    *(float2*)&Tbuf[l5*PADT + i] = make_float2(z[i], z[i+1]);
  __syncthreads();
  #pragma unroll
  for (int i = 0; i < NN; ++i) out[i] = 0.f;
  #pragma unroll 1
  for (int k = 0; k < NN; ++k) {
    float zjk = Tbuf[k*PADT + l5];           // Z[l5][k] (vector read, conflict-free)
    #pragma unroll
    for (int i = 0; i < NN; i += 2) {
      float2 c2 = *(const float2*)&Tbuf[k*PADT + i];   // broadcast b64 reads
      out[i+0] = fmaf(c2.x, zjk, out[i+0]);
      out[i+1] = fmaf(c2.y, zjk, out[i+1]);
    }
  }
}

// ================= K0: weight tables =================
__global__ void k_tables(const float* __restrict__ W, float* __restrict__ tfwd,
                         float* __restrict__ trev, float* __restrict__ wnn) {
  int o = threadIdx.x;
  if (o >= NN) return;
  float w[NN];
  #pragma unroll 1
  for (int i = 0; i < NN; ++i) w[i] = fminf(fmaxf(W[o*NN+i], 0.001f), 0.999f);
  float cs = 0.f;
  #pragma unroll 1
  for (int i = 0; i < NN; ++i) { cs += w[i]; tfwd[o*NN+i] = w[i]/cs; }
  float tot = cs;
  #pragma unroll 1
  for (int i = 0; i < NN; ++i) wnn[o*NN+i] = w[i]/tot;
  cs = 0.f;
  #pragma unroll 1
  for (int i = 0; i < NN; ++i) { cs += w[NN-1-i]; trev[o*NN+i] = w[NN-1-i]/cs; }
}

// ================= K1: Llog[b,i] = logm(X[b,i]) =================
__global__ __launch_bounds__(64) void k_logm(const float* __restrict__ x,
                                             float* __restrict__ llog) {
  __shared__ float Tbuf[2][NN*PADT];
  int lane = threadIdx.x, half = lane >> 5, l5 = lane & 31;
  int P = blockIdx.x*2 + half;                  // b*I + i
  const float* xp = x + (size_t)P*1024 + l5;
  float g[NN];
  #pragma unroll
  for (int i = 0; i < NN; ++i) g[i] = xp[i*NN];
  float nrm;
  jacobi_sweeps(g, nrm);                        // X SPD: columns = U*lam, nrm = lam^2
  float lg   = 0.5f * log2f(fmaxf(nrm, 1e-12f)); // log2(lambda)
  float lnl  = lg * 0.69314718056f;              // ln(lambda)
  float invl = exp2f(-lg);                       // 1/lambda
  float *Tb = Tbuf[half];
  __syncthreads();
  #pragma unroll
  for (int i = 0; i < NN; i += 2)
    *(float2*)&Tb[l5*PADT + i] = make_float2(g[i]*invl, g[i+1]*invl);  // U columns
  Tb[l5*PADT + 32] = lnl;
  __syncthreads();
  float m[NN];
  #pragma unroll
  for (int i = 0; i < NN; ++i) m[i] = 0.f;
  #pragma unroll 1
  for (int k = 0; k < NN; ++k) {
    float coef = Tb[k*PADT + 32] * Tb[k*PADT + l5];  // ln(lam_k) * U[l5][k]
    #pragma unroll
    for (int i = 0; i < NN; i += 2) {
      float2 c2 = *(const float2*)&Tb[k*PADT + i];
      m[i+0] = fmaf(c2.x, coef, m[i+0]);
      m[i+1] = fmaf(c2.y, coef, m[i+1]);
    }
  }
  float* op = llog + (size_t)P*1024 + l5;
  #pragma unroll
  for (int i = 0; i < NN; ++i) op[i*NN] = m[i];
}

// ================= K2: out3 = expm( sum_i wnn[o,i] * Llog[b,i] ) =================
__global__ __launch_bounds__(64) void k_fastfm(const float* __restrict__ llog,
                                               const float* __restrict__ wnn,
                                               float* __restrict__ out3) {
  __shared__ float Tbuf[2][NN*PADT];
  int lane = threadIdx.x, half = lane >> 5, l5 = lane & 31;
  int P = blockIdx.x*2 + half;                  // b*O + o
  int b = P >> 5, o = P & 31;
  float acc[NN];
  #pragma unroll
  for (int i = 0; i < NN; ++i) acc[i] = 0.f;
  const float* lp = llog + (size_t)b*NN*1024 + l5;
  #pragma unroll 1
  for (int i2 = 0; i2 < NN; ++i2) {
    float w = wnn[o*NN + i2];
    const float* q = lp + (size_t)i2*1024;
    #pragma unroll
    for (int i = 0; i < NN; ++i) acc[i] = fmaf(q[i*NN], w, acc[i]);
  }
  // shift by +4I so the matrix is SPD; expm(M) = e^-4 expm(M+4I)
  #pragma unroll
  for (int i = 0; i < NN; ++i) acc[i] += (i == l5) ? 4.0f : 0.0f;
  float nrm;
  jacobi_sweeps(acc, nrm);
  float lg  = 0.5f * log2f(fmaxf(nrm, 1e-12f));
  float lam = exp2f(lg);                        // shifted eigenvalue (lam_true + 4)
  float sc  = expf(0.5f*(lam - 4.0f)) * exp2f(-lg);  // exp(lam_true/2)/lam
  #pragma unroll
  for (int i = 0; i < NN; ++i) acc[i] *= sc;    // Us columns
  float m3[NN];
  zzT(acc, m3, Tbuf[half], l5);                 // Us Us^T
  float* op = out3 + (size_t)P*1024 + l5;
  #pragma unroll
  for (int i = 0; i < NN; ++i) op[i*NN] = m3[i];
}

// ================= K2.5: R[b,i] = chol(X[b,i]), zero-filled upper =================
__global__ __launch_bounds__(64) void k_cholx(const float* __restrict__ x,
                                              float* __restrict__ Rg) {
  int lane = threadIdx.x, half = lane >> 5, l5 = lane & 31;
  int P = blockIdx.x*2 + half;                  // b*I + i
  const float* xp = x + (size_t)P*1024 + l5;
  float m[NN];
  #pragma unroll
  for (int i = 0; i < NN; ++i) m[i] = xp[i*NN];
  #pragma unroll
  for (int j = 0; j < NN; ++j) {
    float bj   = __shfl(m[j], j, 32);
    float invd = rsqrtf(bj);
    float lkj  = m[j] * invd;
    bool isj = (l5 == j), gt = (l5 > j);
    #pragma unroll
    for (int i = j; i < NN; ++i) {
      float bi  = __shfl(m[i], j, 32);
      float lij = bi * invd;
      float upd = fmaf(-lij, lkj, m[i]);
      m[i] = isj ? lij : (gt ? upd : m[i]);
    }
  }
  float* op = Rg + (size_t)P*1024 + l5;
  #pragma unroll
  for (int i = 0; i < NN; ++i) op[i*NN] = (i >= l5) ? m[i] : 0.f;  // lower-tri column
}

// ================= K3a: recursive scan, precomputed-R, low-VGPR schedule =================
// Loop-carried state lives in LDS (L factor), not registers. chol at iteration END;
// first L = R_first directly (chol(R0 R0^T) = R0). rk prefetched where it's dead.
__global__ __launch_bounds__(64, 4) void k_rec_pre(const float* __restrict__ Rg,
    const float* __restrict__ tfwd, const float* __restrict__ trev,
    float* __restrict__ out1, float* __restrict__ out2) {
  __shared__ __align__(16) float Ub[2][NN*PADL];   // union: Lbuf / zzT staging
  int lane = threadIdx.x, half = lane >> 5, l5 = lane & 31;
  int P = blockIdx.x*2 + half;                  // 0..16383
  int dir = P >> 13;                            // B*O = 8192 per direction
  int rem = P & 8191;
  int b = rem >> 5, o = rem & 31;
  const float* tt = dir ? trev : tfwd;
  float tvec = tt[o*NN + l5];                   // lane l5 caches t[o][l5]
  float* outp = (dir ? out2 : out1) + (size_t)(b*NN + o)*1024;
  const float* Rb = Rg + (size_t)b*NN*1024;
  float *Uh = Ub[half];

  float rk[NN];
  {
    // issue first working tile's loads, then set up L while they fly
    int k1 = dir ? (NN-2) : 1;
    const float* rp = Rb + (size_t)k1*1024 + l5;
    #pragma unroll
    for (int i = 0; i < NN; ++i) rk[i] = rp[i*NN];
    const float* r0p = Rb + (size_t)(dir ? (NN-1) : 0)*1024 + l5;
    float r0[NN];
    #pragma unroll
    for (int i = 0; i < NN; ++i) r0[i] = r0p[i*NN];
    #pragma unroll
    for (int i = 0; i < NN; i += 4)
      *(float4*)&Uh[l5*PADL + i] = make_float4(r0[i], r0[i+1], r0[i+2], r0[i+3]);
    __syncthreads();
    Uh[l5*PADL + 32] = __builtin_amdgcn_rcpf(Uh[l5*PADL + l5]);  // own diag from LDS
    __syncthreads();
  }
  float m[NN];
  #pragma unroll 1
  for (int j = 1; j < NN; ++j) {
    float tv = __shfl(tvec, j, 32);
    trsv32(rk, Uh);                               // G = L^-1 R_k
    float nrm;
    jacobi_sweeps(rk, nrm);                       // G = U*sig, nrm = sig^2 = eig(C)
    // Us = U * lam^{t/2} = g * lam^{(t-1)/2},  lam = nrm
    float lg = log2f(fmaxf(nrm, 1e-12f));
    float sc = exp2f(lg * 0.5f * (tv - 1.0f));
    #pragma unroll
    for (int i = 0; i < NN; ++i) rk[i] *= sc;
    float z[NN];
    trmul_L(rk, z, Uh);                           // Z = L * Us; rk dead after this
    if (j < NN-1) {                               // prefetch next tile under zzT+chol
      int kn = dir ? (NN-1-(j+1)) : (j+1);
      const float* rp = Rb + (size_t)kn*1024 + l5;
      #pragma unroll
      for (int i = 0; i < NN; ++i) rk[i] = rp[i*NN];
    }
    zzT(z, m, Uh, l5);                            // M' = Z Z^T (L dead; union safe)
    if (j < NN-1) cholesky32(m, Uh, l5);          // L for next iteration; m dead after
  }
  #pragma unroll
  for (int i = 0; i < NN; ++i) outp[i*NN + l5] = m[i];
}

// ================= K3b: fallback (ws too small): round-2 structure =================
__global__ __launch_bounds__(64) void k_rec_fb(const float* __restrict__ x,
    const float* __restrict__ tfwd, const float* __restrict__ trev,
    float* __restrict__ out1, float* __restrict__ out2) {
  __shared__ __align__(16) float Lbuf[2][NN*PADL];
  __shared__ float Tbuf[2][NN*PADT];
  int lane = threadIdx.x, half = lane >> 5, l5 = lane & 31;
  int P = blockIdx.x*2 + half;
  int dir = P >> 13;
  int rem = P & 8191;
  int b = rem >> 5, o = rem & 31;
  const float* tt = dir ? trev : tfwd;
  float* outp = (dir ? out2 : out1) + (size_t)(b*NN + o)*1024;
  const float* xb = x + (size_t)b*NN*1024;
  float *Lb = Lbuf[half], *Tb = Tbuf[half];

  float m[NN];
  {
    const float* xp = xb + (size_t)(dir ? (NN-1) : 0)*1024 + l5;
    #pragma unroll
    for (int i = 0; i < NN; ++i) m[i] = xp[i*NN];
  }
  #pragma unroll 1
  for (int j = 1; j < NN; ++j) {
    int k = dir ? (NN-1-j) : j;
    float xk[NN];
    const float* xp = xb + (size_t)k*1024 + l5;
    #pragma unroll
    for (int i = 0; i < NN; ++i) xk[i] = xp[i*NN];
    float tv = tt[o*NN + j];

    cholesky32(m, Lb, l5);
    trsv32(xk, Lb);
    transpose32(xk, Tb, l5);
    trsv32(xk, Lb);                               // C = L^-1 X L^-T
    float nrm;
    jacobi_sweeps(xk, nrm);                       // C = U*lam, nrm = lam^2
    float lg = 0.5f * log2f(fmaxf(nrm, 1e-12f));
    float sc = exp2f(lg * (0.5f*tv - 1.0f));
    #pragma unroll
    for (int i = 0; i < NN; ++i) xk[i] *= sc;
    float z[NN];
    trmul_L(xk, z, Lb);
    zzT(z, m, Tb, l5);
  }
  #pragma unroll
  for (int i = 0; i < NN; ++i) outp[i*NN + l5] = m[i];
}

extern "C" void kernel_launch(void* const* d_in, const int* in_sizes, int n_in,
                              void* d_out, int out_size, void* d_ws, size_t ws_size,
                              hipStream_t stream) {
  (void)in_sizes; (void)n_in; (void)out_size;
  const float* x = (const float*)d_in[0];
  const float* W = (const float*)d_in[1];
  float* out  = (float*)d_out;
  float* ws   = (float*)d_ws;
  float* tfwd = ws;
  float* trev = ws + 1024;
  float* wnn  = ws + 2048;
  float* Rg   = ws + 3072;                       // 32 MiB if available
  float* out1 = out;
  float* out2 = out + 8388608;
  float* out3 = out + 16777216;
  float* llog = out1;                            // consumed by k_fastfm before k_rec_*

  const size_t need = (size_t)(3072 + 8388608) * sizeof(float);
  const bool pre = (ws_size >= need);

  hipLaunchKernelGGL(k_tables,    dim3(1),    dim3(64), 0, stream, W, tfwd, trev, wnn);
  hipLaunchKernelGGL(k_logm,      dim3(4096), dim3(64), 0, stream, x, llog);
  hipLaunchKernelGGL(k_fastfm,    dim3(4096), dim3(64), 0, stream, llog, wnn, out3);
  if (pre) {
    hipLaunchKernelGGL(k_cholx,   dim3(4096), dim3(64), 0, stream, x, Rg);
    hipLaunchKernelGGL(k_rec_pre, dim3(8192), dim3(64), 0, stream, Rg, tfwd, trev, out1, out2);
  } else {
    hipLaunchKernelGGL(k_rec_fb,  dim3(8192), dim3(64), 0, stream, x, tfwd, trev, out1, out2);
  }
}

// Round 8
// 25298.967 us; speedup vs baseline: 1.2789x; 1.0618x over previous
//
#include <hip/hip_runtime.h>
#include <math.h>

#define NN 32
#define PADL 36   // L buffer column stride (f32): float4-aligned chunks, +32 slot holds 1/diag
#define PADT 34   // transpose-style stride: even (float2-aligned), <=2-way conflicts (free)
#define NSWEEP 6

// ---------------- one-sided Jacobi (XOR cyclic ordering, EXACT rotation updates) --------
// g[]: this lane's column of a 32x32 matrix G (lane l5 of each 32-half owns col l5).
// Orthogonalizes columns (right rotations): on exit g = U*sigma, nrm = sigma^2 (exact).
// For symmetric input C: sigma = eigenvalue; for general G: sigma^2 = eig of G G^T.
__device__ __forceinline__ void jacobi_sweeps(float g[NN], float &nrm) {
  {
    float a0=0.f,a1=0.f,a2=0.f,a3=0.f;
    #pragma unroll
    for (int i = 0; i < NN; i += 4) {
      a0 = fmaf(g[i+0],g[i+0],a0); a1 = fmaf(g[i+1],g[i+1],a1);
      a2 = fmaf(g[i+2],g[i+2],a2); a3 = fmaf(g[i+3],g[i+3],a3);
    }
    nrm = (a0+a1)+(a2+a3);
  }
  const int l5 = threadIdx.x & 31;
  #pragma unroll 1
  for (int sw = 0; sw < NSWEEP; ++sw) {
    bool act = false;
    #pragma unroll 1
    for (int m = 1; m < NN; ++m) {
      float p[NN];
      #pragma unroll
      for (int i = 0; i < NN; ++i) p[i] = __shfl_xor(g[i], m);
      float d0=0.f,d1=0.f,d2=0.f,d3=0.f;
      #pragma unroll
      for (int i = 0; i < NN; i += 4) {
        d0 = fmaf(g[i+0], p[i+0], d0); d1 = fmaf(g[i+1], p[i+1], d1);
        d2 = fmaf(g[i+2], p[i+2], d2); d3 = fmaf(g[i+3], p[i+3], d3);
      }
      float d = (d0+d1)+(d2+d3);
      float other = __shfl_xor(nrm, m);
      const bool isP = (((l5 ^ m) & 31) > l5);   // partner higher index -> we play "p"
      float pn = isP ? nrm : other;       // shared p-perspective (identical on the pair)
      float qn = isP ? other : nrm;
      float delta = pn - qn;
      float dd = d * d;
      act = act || (dd > 1e-10f * (pn * qn));   // |cos theta| > 1e-5: not converged
      float r2 = fmaf(delta, delta, 4.f * dd);
      float R  = r2 * rsqrtf(fmaxf(r2, 1e-37f));   // sqrt(r2), 0-safe
      float den = delta + copysignf(R + 1e-30f, delta);
      float t = (-2.f * d) * __builtin_amdgcn_rcpf(den);  // small-|t| root of d t^2 - delta t - d = 0
      float c = rsqrtf(fmaf(t, t, 1.f));
      float s = t * c;
      float sg = isP ? -s : s;            // p: c*gp - s*gq ; q: c*gq + s*gp
      #pragma unroll
      for (int i = 0; i < NN; ++i) g[i] = fmaf(sg, p[i], c*g[i]);
      float csd2 = 2.f*c*s*d;
      nrm = c*c*nrm + s*s*other + (isP ? -csd2 : csd2);
    }
    if (!__any(act)) break;               // wave-wide convergence (both halves)
  }
  // exact norm recompute (analytic updates drift slightly)
  float a0=0.f,a1=0.f,a2=0.f,a3=0.f;
  #pragma unroll
  for (int i = 0; i < NN; i += 4) {
    a0 = fmaf(g[i+0],g[i+0],a0); a1 = fmaf(g[i+1],g[i+1],a1);
    a2 = fmaf(g[i+2],g[i+2],a2); a3 = fmaf(g[i+3],g[i+3],a3);
  }
  nrm = (a0+a1)+(a2+a3);
}

// ---------------- Cholesky: m[] (col of SPD M, in place -> col of L) ----------------
// gt guard is REQUIRED (finalized columns must not take Schur updates).
// Lbuf[c*PADL + r] = L[r][c]; 1/L[j][j] at Lbuf[j*PADL+32].
__device__ __forceinline__ void cholesky32(float m[NN], float *Lbuf, int l5) {
  float myinvd = 0.f;
  #pragma unroll
  for (int j = 0; j < NN; ++j) {
    float bj   = __shfl(m[j], j, 32);      // current Schur diagonal
    float invd = rsqrtf(bj);               // 1/L[j][j]
    float lkj  = m[j] * invd;              // own L[lane][j] (valid lanes >= j by symmetry)
    bool isj = (l5 == j), gt = (l5 > j);
    myinvd = isj ? invd : myinvd;
    #pragma unroll
    for (int i = j; i < NN; ++i) {
      float bi  = __shfl(m[i], j, 32);
      float lij = bi * invd;
      float upd = fmaf(-lij, lkj, m[i]);
      m[i] = isj ? lij : (gt ? upd : m[i]);  // lanes < j: column final, DO NOT touch
    }
  }
  #pragma unroll
  for (int i = 0; i < NN; i += 4)
    *(float4*)&Lbuf[l5*PADL + i] = make_float4(m[i], m[i+1], m[i+2], m[i+3]);
  Lbuf[l5*PADL + 32] = myinvd;
}

// ---------------- forward triangular solve: x := L^-1 x (x = lane-owned RHS column) ----
__device__ __forceinline__ void trsv32(float x[NN], const float *Lbuf) {
  #pragma unroll
  for (int j = 0; j < NN; ++j) {
    float yj = x[j] * Lbuf[j*PADL + 32];
    x[j] = yj;
    #pragma unroll
    for (int i0 = ((j+1) & ~3); i0 < NN; i0 += 4) {
      float4 Lc = *(const float4*)&Lbuf[j*PADL + i0];
      if (i0+0 > j) x[i0+0] = fmaf(-Lc.x, yj, x[i0+0]);
      if (i0+1 > j) x[i0+1] = fmaf(-Lc.y, yj, x[i0+1]);
      if (i0+2 > j) x[i0+2] = fmaf(-Lc.z, yj, x[i0+2]);
      if (i0+3 > j) x[i0+3] = fmaf(-Lc.w, yj, x[i0+3]);
    }
  }
}

// ---------------- 32x32 transpose of lane-owned columns via LDS (fallback path) --------
__device__ __forceinline__ void transpose32(float x[NN], float *Tbuf, int l5) {
  __syncthreads();
  #pragma unroll
  for (int i = 0; i < NN; i += 2)
    *(float2*)&Tbuf[l5*PADT + i] = make_float2(x[i], x[i+1]);
  __syncthreads();
  #pragma unroll
  for (int i = 0; i < NN; ++i) x[i] = Tbuf[i*PADT + l5];
}

// ---------------- z = L * us (L lower-tri from Lbuf, us lane-owned column) ----------
// k-outer: us[k] dies as z fills -> combined liveness stays ~32-64, not 64 flat.
__device__ __forceinline__ void trmul_L(const float us[NN], float z[NN], const float *Lbuf) {
  #pragma unroll
  for (int i = 0; i < NN; ++i) z[i] = 0.f;
  #pragma unroll
  for (int k = 0; k < NN; ++k) {
    float uk = us[k];
    #pragma unroll
    for (int i0 = (k & ~3); i0 < NN; i0 += 4) {
      float4 Lc = *(const float4*)&Lbuf[k*PADL + i0];
      if (i0+0 >= k) z[i0+0] = fmaf(Lc.x, uk, z[i0+0]);
      if (i0+1 >= k) z[i0+1] = fmaf(Lc.y, uk, z[i0+1]);
      if (i0+2 >= k) z[i0+2] = fmaf(Lc.z, uk, z[i0+2]);
      if (i0+3 >= k) z[i0+3] = fmaf(Lc.w, uk, z[i0+3]);
    }
  }
}

// ---------------- out := Z * Z^T (Z = lane-owned columns), via LDS (PADT stride) -------
__device__ __forceinline__ void zzT(const float z[NN], float out[NN], float *Tbuf, int l5) {
  __syncthreads();
  #pragma unroll
  for (int i = 0; i < NN; i += 2)
    *(float2*)&Tbuf[l5*PADT + i] = make_float2(z[i], z[i+1]);
  __syncthreads();
  #pragma unroll
  for (int i = 0; i < NN; ++i) out[i] = 0.f;
  #pragma unroll 1
  for (int k = 0; k < NN; ++k) {
    float zjk = Tbuf[k*PADT + l5];           // Z[l5][k] (vector read, conflict-free)
    #pragma unroll
    for (int i = 0; i < NN; i += 2) {
      float2 c2 = *(const float2*)&Tbuf[k*PADT + i];   // broadcast b64 reads
      out[i+0] = fmaf(c2.x, zjk, out[i+0]);
      out[i+1] = fmaf(c2.y, zjk, out[i+1]);
    }
  }
}

// ================= K0: weight tables =================
__global__ void k_tables(const float* __restrict__ W, float* __restrict__ tfwd,
                         float* __restrict__ trev, float* __restrict__ wnn) {
  int o = threadIdx.x;
  if (o >= NN) return;
  float w[NN];
  #pragma unroll 1
  for (int i = 0; i < NN; ++i) w[i] = fminf(fmaxf(W[o*NN+i], 0.001f), 0.999f);
  float cs = 0.f;
  #pragma unroll 1
  for (int i = 0; i < NN; ++i) { cs += w[i]; tfwd[o*NN+i] = w[i]/cs; }
  float tot = cs;
  #pragma unroll 1
  for (int i = 0; i < NN; ++i) wnn[o*NN+i] = w[i]/tot;
  cs = 0.f;
  #pragma unroll 1
  for (int i = 0; i < NN; ++i) { cs += w[NN-1-i]; trev[o*NN+i] = w[NN-1-i]/cs; }
}

// ================= K1: Llog[b,i] = logm(X[b,i]) =================
__global__ __launch_bounds__(64) void k_logm(const float* __restrict__ x,
                                             float* __restrict__ llog) {
  __shared__ float Tbuf[2][NN*PADT];
  int lane = threadIdx.x, half = lane >> 5, l5 = lane & 31;
  int P = blockIdx.x*2 + half;                  // b*I + i
  const float* xp = x + (size_t)P*1024 + l5;
  float g[NN];
  #pragma unroll
  for (int i = 0; i < NN; ++i) g[i] = xp[i*NN];
  float nrm;
  jacobi_sweeps(g, nrm);                        // X SPD: columns = U*lam, nrm = lam^2
  float lg   = 0.5f * log2f(fmaxf(nrm, 1e-12f)); // log2(lambda)
  float lnl  = lg * 0.69314718056f;              // ln(lambda)
  float invl = exp2f(-lg);                       // 1/lambda
  float *Tb = Tbuf[half];
  __syncthreads();
  #pragma unroll
  for (int i = 0; i < NN; i += 2)
    *(float2*)&Tb[l5*PADT + i] = make_float2(g[i]*invl, g[i+1]*invl);  // U columns
  Tb[l5*PADT + 32] = lnl;
  __syncthreads();
  float m[NN];
  #pragma unroll
  for (int i = 0; i < NN; ++i) m[i] = 0.f;
  #pragma unroll 1
  for (int k = 0; k < NN; ++k) {
    float coef = Tb[k*PADT + 32] * Tb[k*PADT + l5];  // ln(lam_k) * U[l5][k]
    #pragma unroll
    for (int i = 0; i < NN; i += 2) {
      float2 c2 = *(const float2*)&Tb[k*PADT + i];
      m[i+0] = fmaf(c2.x, coef, m[i+0]);
      m[i+1] = fmaf(c2.y, coef, m[i+1]);
    }
  }
  float* op = llog + (size_t)P*1024 + l5;
  #pragma unroll
  for (int i = 0; i < NN; ++i) op[i*NN] = m[i];
}

// ================= K2: out3 = expm( sum_i wnn[o,i] * Llog[b,i] ) =================
__global__ __launch_bounds__(64) void k_fastfm(const float* __restrict__ llog,
                                               const float* __restrict__ wnn,
                                               float* __restrict__ out3) {
  __shared__ float Tbuf[2][NN*PADT];
  int lane = threadIdx.x, half = lane >> 5, l5 = lane & 31;
  int P = blockIdx.x*2 + half;                  // b*O + o
  int b = P >> 5, o = P & 31;
  float acc[NN];
  #pragma unroll
  for (int i = 0; i < NN; ++i) acc[i] = 0.f;
  const float* lp = llog + (size_t)b*NN*1024 + l5;
  #pragma unroll 1
  for (int i2 = 0; i2 < NN; ++i2) {
    float w = wnn[o*NN + i2];
    const float* q = lp + (size_t)i2*1024;
    #pragma unroll
    for (int i = 0; i < NN; ++i) acc[i] = fmaf(q[i*NN], w, acc[i]);
  }
  // shift by +4I so the matrix is SPD; expm(M) = e^-4 expm(M+4I)
  #pragma unroll
  for (int i = 0; i < NN; ++i) acc[i] += (i == l5) ? 4.0f : 0.0f;
  float nrm;
  jacobi_sweeps(acc, nrm);
  float lg  = 0.5f * log2f(fmaxf(nrm, 1e-12f));
  float lam = exp2f(lg);                        // shifted eigenvalue (lam_true + 4)
  float sc  = expf(0.5f*(lam - 4.0f)) * exp2f(-lg);  // exp(lam_true/2)/lam
  #pragma unroll
  for (int i = 0; i < NN; ++i) acc[i] *= sc;    // Us columns
  float m3[NN];
  zzT(acc, m3, Tbuf[half], l5);                 // Us Us^T
  float* op = out3 + (size_t)P*1024 + l5;
  #pragma unroll
  for (int i = 0; i < NN; ++i) op[i*NN] = m3[i];
}

// ================= K2.5: R[b,i] = chol(X[b,i]), zero-filled upper =================
__global__ __launch_bounds__(64) void k_cholx(const float* __restrict__ x,
                                              float* __restrict__ Rg) {
  int lane = threadIdx.x, half = lane >> 5, l5 = lane & 31;
  int P = blockIdx.x*2 + half;                  // b*I + i
  const float* xp = x + (size_t)P*1024 + l5;
  float m[NN];
  #pragma unroll
  for (int i = 0; i < NN; ++i) m[i] = xp[i*NN];
  #pragma unroll
  for (int j = 0; j < NN; ++j) {
    float bj   = __shfl(m[j], j, 32);
    float invd = rsqrtf(bj);
    float lkj  = m[j] * invd;
    bool isj = (l5 == j), gt = (l5 > j);
    #pragma unroll
    for (int i = j; i < NN; ++i) {
      float bi  = __shfl(m[i], j, 32);
      float lij = bi * invd;
      float upd = fmaf(-lij, lkj, m[i]);
      m[i] = isj ? lij : (gt ? upd : m[i]);
    }
  }
  float* op = Rg + (size_t)P*1024 + l5;
  #pragma unroll
  for (int i = 0; i < NN; ++i) op[i*NN] = (i >= l5) ? m[i] : 0.f;  // lower-tri column
}

// ================= K3a: recursive scan, precomputed-R, VGPR-capped ~85 =================
// Loop-carried state lives in LDS (L factor). chol at iteration END; first L = R_first
// (chol(R0 R0^T) = R0). NO rk prefetch: loads issue right before trsv and drain during
// the serial solve -> same hiding without the 32-reg live range across zzT+chol.
__global__ __launch_bounds__(64, 3) void k_rec_pre(const float* __restrict__ Rg,
    const float* __restrict__ tfwd, const float* __restrict__ trev,
    float* __restrict__ out1, float* __restrict__ out2) {
  __shared__ __align__(16) float Ub[2][NN*PADL];   // union: Lbuf / zzT staging
  int lane = threadIdx.x, half = lane >> 5, l5 = lane & 31;
  int P = blockIdx.x*2 + half;                  // 0..16383
  int dir = P >> 13;                            // B*O = 8192 per direction
  int rem = P & 8191;
  int b = rem >> 5, o = rem & 31;
  const float* tt = dir ? trev : tfwd;
  float tvec = tt[o*NN + l5];                   // lane l5 caches t[o][l5]
  float* outp = (dir ? out2 : out1) + (size_t)(b*NN + o)*1024;
  const float* Rb = Rg + (size_t)b*NN*1024;
  float *Uh = Ub[half];

  {
    // L0 = R_first straight into LDS (only r0 live here)
    const float* r0p = Rb + (size_t)(dir ? (NN-1) : 0)*1024 + l5;
    float r0[NN];
    #pragma unroll
    for (int i = 0; i < NN; ++i) r0[i] = r0p[i*NN];
    #pragma unroll
    for (int i = 0; i < NN; i += 4)
      *(float4*)&Uh[l5*PADL + i] = make_float4(r0[i], r0[i+1], r0[i+2], r0[i+3]);
    __syncthreads();
    Uh[l5*PADL + 32] = __builtin_amdgcn_rcpf(Uh[l5*PADL + l5]);  // own diag from LDS
    __syncthreads();
  }
  float m[NN];
  #pragma unroll 1
  for (int j = 1; j < NN; ++j) {
    float tv = __shfl(tvec, j, 32);
    float rk[NN];
    {
      int k = dir ? (NN-1-j) : j;
      const float* rp = Rb + (size_t)k*1024 + l5;
      #pragma unroll
      for (int i = 0; i < NN; ++i) rk[i] = rp[i*NN];
    }
    trsv32(rk, Uh);                               // G = L^-1 R_k (consumes loads serially)
    float nrm;
    jacobi_sweeps(rk, nrm);                       // G = U*sig, nrm = sig^2 = eig(C)
    // Us = U * lam^{t/2} = g * lam^{(t-1)/2},  lam = nrm
    float lg = log2f(fmaxf(nrm, 1e-12f));
    float sc = exp2f(lg * 0.5f * (tv - 1.0f));
    #pragma unroll
    for (int i = 0; i < NN; ++i) rk[i] *= sc;
    float z[NN];
    trmul_L(rk, z, Uh);                           // Z = L * Us; rk dead after this
    zzT(z, m, Uh, l5);                            // M' = Z Z^T (L dead; union safe)
    if (j < NN-1) cholesky32(m, Uh, l5);          // L for next iteration; m dead after
  }
  #pragma unroll
  for (int i = 0; i < NN; ++i) outp[i*NN + l5] = m[i];
}

// ================= K3b: fallback (ws too small): round-2 structure =================
__global__ __launch_bounds__(64) void k_rec_fb(const float* __restrict__ x,
    const float* __restrict__ tfwd, const float* __restrict__ trev,
    float* __restrict__ out1, float* __restrict__ out2) {
  __shared__ __align__(16) float Lbuf[2][NN*PADL];
  __shared__ float Tbuf[2][NN*PADT];
  int lane = threadIdx.x, half = lane >> 5, l5 = lane & 31;
  int P = blockIdx.x*2 + half;
  int dir = P >> 13;
  int rem = P & 8191;
  int b = rem >> 5, o = rem & 31;
  const float* tt = dir ? trev : tfwd;
  float* outp = (dir ? out2 : out1) + (size_t)(b*NN + o)*1024;
  const float* xb = x + (size_t)b*NN*1024;
  float *Lb = Lbuf[half], *Tb = Tbuf[half];

  float m[NN];
  {
    const float* xp = xb + (size_t)(dir ? (NN-1) : 0)*1024 + l5;
    #pragma unroll
    for (int i = 0; i < NN; ++i) m[i] = xp[i*NN];
  }
  #pragma unroll 1
  for (int j = 1; j < NN; ++j) {
    int k = dir ? (NN-1-j) : j;
    float xk[NN];
    const float* xp = xb + (size_t)k*1024 + l5;
    #pragma unroll
    for (int i = 0; i < NN; ++i) xk[i] = xp[i*NN];
    float tv = tt[o*NN + j];

    cholesky32(m, Lb, l5);
    trsv32(xk, Lb);
    transpose32(xk, Tb, l5);
    trsv32(xk, Lb);                               // C = L^-1 X L^-T
    float nrm;
    jacobi_sweeps(xk, nrm);                       // C = U*lam, nrm = lam^2
    float lg = 0.5f * log2f(fmaxf(nrm, 1e-12f));
    float sc = exp2f(lg * (0.5f*tv - 1.0f));
    #pragma unroll
    for (int i = 0; i < NN; ++i) xk[i] *= sc;
    float z[NN];
    trmul_L(xk, z, Lb);
    zzT(z, m, Tb, l5);
  }
  #pragma unroll
  for (int i = 0; i < NN; ++i) outp[i*NN + l5] = m[i];
}

extern "C" void kernel_launch(void* const* d_in, const int* in_sizes, int n_in,
                              void* d_out, int out_size, void* d_ws, size_t ws_size,
                              hipStream_t stream) {
  (void)in_sizes; (void)n_in; (void)out_size;
  const float* x = (const float*)d_in[0];
  const float* W = (const float*)d_in[1];
  float* out  = (float*)d_out;
  float* ws   = (float*)d_ws;
  float* tfwd = ws;
  float* trev = ws + 1024;
  float* wnn  = ws + 2048;
  float* Rg   = ws + 3072;                       // 32 MiB if available
  float* out1 = out;
  float* out2 = out + 8388608;
  float* out3 = out + 16777216;
  float* llog = out1;                            // consumed by k_fastfm before k_rec_*

  const size_t need = (size_t)(3072 + 8388608) * sizeof(float);
  const bool pre = (ws_size >= need);

  hipLaunchKernelGGL(k_tables,    dim3(1),    dim3(64), 0, stream, W, tfwd, trev, wnn);
  hipLaunchKernelGGL(k_logm,      dim3(4096), dim3(64), 0, stream, x, llog);
  hipLaunchKernelGGL(k_fastfm,    dim3(4096), dim3(64), 0, stream, llog, wnn, out3);
  if (pre) {
    hipLaunchKernelGGL(k_cholx,   dim3(4096), dim3(64), 0, stream, x, Rg);
    hipLaunchKernelGGL(k_rec_pre, dim3(8192), dim3(64), 0, stream, Rg, tfwd, trev, out1, out2);
  } else {
    hipLaunchKernelGGL(k_rec_fb,  dim3(8192), dim3(64), 0, stream, x, tfwd, trev, out1, out2);
  }
}